// Round 8
// baseline (2201.556 us; speedup 1.0000x reference)
//
#include <hip/hip_runtime.h>
#include <hip/hip_bf16.h>
#include <math.h>

#define B_ 128
#define L_ 196
#define D_ 512
#define T_ 20
#define V_ 10000
#define E_ 256
#define H_ 512
#define A_ 512
#define TM1 19
#define ROWS (TM1*B_)      /* 2432 */
#define G4H 2048
#define KCAT 1024
#define LH 98
#define NBLK 256

typedef unsigned short ushort_t;
typedef __attribute__((ext_vector_type(8))) short bf16x8;
typedef __attribute__((ext_vector_type(4))) float f32x4;

__device__ __forceinline__ float fast_tanh(float x){
    float ax = fabsf(x);
    float e = __expf(-2.f*ax);
    float r = __builtin_amdgcn_rcpf(1.f + e);
    return copysignf((1.f - e)*r, x);
}
__device__ __forceinline__ float sigmoidf_(float x){
    return __builtin_amdgcn_rcpf(1.f + __expf(-x));
}
__device__ __forceinline__ ushort_t f2b(float f){
    union{float f; unsigned u;} x; x.f = f;
    unsigned r = x.u + 0x7fffu + ((x.u>>16)&1u);
    return (ushort_t)(r>>16);
}
__device__ __forceinline__ float b2f(ushort_t h){
    union{unsigned u; float f;} x; x.u = ((unsigned)h)<<16;
    return x.f;
}
__device__ __forceinline__ float b2f_lo(unsigned u){ union{unsigned u; float f;} x; x.u = u<<16; return x.f; }
__device__ __forceinline__ float b2f_hi(unsigned u){ union{unsigned u; float f;} x; x.u = u & 0xffff0000u; return x.f; }

// ================= bf16 MFMA GEMM: C = A @ BT^T (+bias), swizzled LDS =================
template<int OUT_BF16, int HAS_BIAS, int NT, int SWZ>
__global__ __launch_bounds__(256)
void gemm_mfma(const ushort_t* __restrict__ A, int lda,
               const ushort_t* __restrict__ BT, int ldb,
               void* __restrict__ Cout, int ldc,
               int N, int K, const float* __restrict__ bias)
{
    __shared__ ushort_t As[128*32];
    __shared__ ushort_t Bs[128*32];
    int bm, bn;
    if (SWZ){
        int bid = blockIdx.x;                 // 0..1519
        int swz = (bid & 7)*190 + (bid >> 3); // XCD-contiguous chunks
        int mt = swz % 19, nt = swz / 19;     // nt 0..79
        if (nt >= 79) return;
        bm = mt*128; bn = nt*128;
    } else {
        bm = blockIdx.y * 128; bn = blockIdx.x * 128;
    }
    const int tid = threadIdx.x;
    const int lane = tid & 63;
    const int wave = tid >> 6;
    const int wm = (wave >> 1) * 64;
    const int wn = (wave & 1) * 64;
    const int lrow = lane & 15;
    const int lk8  = (lane >> 4) * 8;
    const int srow = tid >> 2;
    const int skq  = ((tid & 3) * 8) ^ ((srow & 3) << 3);   // write-side swizzle
    const int skq0 = (tid & 3) * 8;

    f32x4 acc[4][4];
    #pragma unroll
    for (int i=0;i<4;i++)
        #pragma unroll
        for (int j=0;j<4;j++) acc[i][j] = (f32x4){0.f,0.f,0.f,0.f};

    const ushort_t* Abase = A  + (size_t)(bm+srow)*lda + skq0;
    const ushort_t* Bbase = BT + (size_t)(bn+srow)*ldb + skq0;

    for (int k0 = 0; k0 < K; k0 += 32) {
        int4 a0 = *(const int4*)(Abase + k0);
        int4 a1 = *(const int4*)(Abase + (size_t)64*lda + k0);
        int4 b0 = *(const int4*)(Bbase + k0);
        int4 b1 = *(const int4*)(Bbase + (size_t)64*ldb + k0);
        __syncthreads();
        *(int4*)&As[srow*32 + skq]      = a0;
        *(int4*)&As[(srow+64)*32 + skq] = a1;
        *(int4*)&Bs[srow*32 + skq]      = b0;
        *(int4*)&Bs[(srow+64)*32 + skq] = b1;
        __syncthreads();
        bf16x8 af[4], bfr[4];
        #pragma unroll
        for (int i=0;i<4;i++){
            int r = wm + i*16 + lrow;
            af[i]  = *(bf16x8*)&As[r*32 + (lk8 ^ ((r & 3) << 3))];
        }
        #pragma unroll
        for (int j=0;j<4;j++){
            int r = wn + j*16 + lrow;
            bfr[j] = *(bf16x8*)&Bs[r*32 + (lk8 ^ ((r & 3) << 3))];
        }
        #pragma unroll
        for (int i=0;i<4;i++)
            #pragma unroll
            for (int j=0;j<4;j++)
                acc[i][j] = __builtin_amdgcn_mfma_f32_16x16x32_bf16(af[i], bfr[j], acc[i][j], 0, 0, 0);
    }

    const int rq = (lane >> 4) * 4;
    #pragma unroll
    for (int j=0;j<4;j++){
        int col = bn + wn + j*16 + lrow;
        if (col >= N) continue;
        float bv = HAS_BIAS ? bias[col] : 0.f;
        #pragma unroll
        for (int i=0;i<4;i++){
            #pragma unroll
            for (int q=0;q<4;q++){
                int row = bm + wm + i*16 + rq + q;
                float v = acc[i][j][q] + bv;
                if (OUT_BF16) ((ushort_t*)Cout)[(size_t)row*ldc + col] = f2b(v);
                else if (NT)  __builtin_nontemporal_store(v, &((float*)Cout)[(size_t)row*ldc + col]);
                else          ((float*)Cout)[(size_t)row*ldc + col] = v;
            }
        }
    }
}

// ============ f32 tile GEMM (init path): C = tanh(A@B + bias), z picks job ============
__global__ __launch_bounds__(256) void gemm64t2(const float* __restrict__ A, int lda,
                       const float* __restrict__ B0, const float* __restrict__ B1, int ldb,
                       float* __restrict__ C0, float* __restrict__ C1, int ldc,
                       const float* __restrict__ bias0, const float* __restrict__ bias1)
{
    const float* Bm  = blockIdx.z ? B1 : B0;
    float* C         = blockIdx.z ? C1 : C0;
    const float* bias= blockIdx.z ? bias1 : bias0;
    __shared__ float As[16][65];
    __shared__ float Bs[16][65];
    int bm = blockIdx.y*64, bn = blockIdx.x*64;
    int tid = threadIdx.x;
    int tx = tid & 15, ty = tid >> 4;
    float acc[4][4] = {};
    for (int k0 = 0; k0 < D_; k0 += 16) {
        {
            int r  = tid >> 2;
            int kq = (tid & 3) * 4;
            float4 va = *(const float4*)(A + (size_t)(bm+r)*lda + k0 + kq);
            As[kq+0][r]=va.x; As[kq+1][r]=va.y; As[kq+2][r]=va.z; As[kq+3][r]=va.w;
        }
        {
            int kk = tid >> 4;
            int nq = (tid & 15) * 4;
            float4 vb = *(const float4*)(Bm + (size_t)(k0+kk)*ldb + bn + nq);
            Bs[kk][nq+0]=vb.x; Bs[kk][nq+1]=vb.y; Bs[kk][nq+2]=vb.z; Bs[kk][nq+3]=vb.w;
        }
        __syncthreads();
        #pragma unroll
        for (int k = 0; k < 16; ++k) {
            float a0[4], b0[4];
            #pragma unroll
            for (int i=0;i<4;i++) a0[i] = As[k][ty*4+i];
            #pragma unroll
            for (int j=0;j<4;j++) b0[j] = Bs[k][tx*4+j];
            #pragma unroll
            for (int i=0;i<4;i++)
                #pragma unroll
                for (int j=0;j<4;j++)
                    acc[i][j] = fmaf(a0[i], b0[j], acc[i][j]);
        }
        __syncthreads();
    }
    #pragma unroll
    for (int i=0;i<4;i++){
        int row = bm + ty*4 + i;
        #pragma unroll
        for (int j=0;j<4;j++){
            int col = bn + tx*4 + j;
            C[(size_t)row*ldc + col] = fast_tanh(acc[i][j] + bias[col]);
        }
    }
}

// ================= combined transpose+cvt (all weights in one launch) =================
struct TJob { const float* src; const float* src2; ushort_t* dst;
              int lds, Ksz, Nsz, koff, ldk, nx, nblk; };
struct TJobs { TJob j[6]; };

__global__ __launch_bounds__(256) void combo_trans_k(TJobs J){
    __shared__ float t[32][33];
    int bid = blockIdx.x;
    int ji = 0;
    while (bid >= J.j[ji].nblk){ bid -= J.j[ji].nblk; ji++; }
    const TJob jb = J.j[ji];
    int n0 = (bid % jb.nx)*32, k0 = (bid / jb.nx)*32;
    int tx = threadIdx.x & 31, ty = threadIdx.x >> 5;
    #pragma unroll
    for (int kk = ty; kk < 32; kk += 8){
        int k = k0 + kk, n = n0 + tx;
        float v = 0.f;
        if (k < jb.Ksz && n < jb.Nsz){
            v = jb.src[(size_t)k*jb.lds + n];
            if (jb.src2) v += jb.src2[(size_t)k*jb.lds + n];
        }
        t[kk][tx] = v;
    }
    __syncthreads();
    #pragma unroll
    for (int nn = ty; nn < 32; nn += 8){
        int n = n0 + nn, k = k0 + tx;
        if (k < jb.Ksz) jb.dst[(size_t)n*jb.ldk + jb.koff + k] = f2b(t[tx][nn]);
    }
}

// one pass over a: column means + bf16 copy; block 256 also does bias4h + barrier init
__global__ __launch_bounds__(256) void mean_cvt_k(const float* __restrict__ a, ushort_t* __restrict__ a_b,
                                                  float* __restrict__ mc,
                                                  const float* __restrict__ b_ih, const float* __restrict__ b_hh,
                                                  float* __restrict__ bias4h, unsigned* __restrict__ bars){
    if (blockIdx.x == 256){
        for (int k = threadIdx.x; k < G4H; k += 256) bias4h[k] = b_ih[k] + b_hh[k];
        if (threadIdx.x < B_ + 1) bars[threadIdx.x] = 0u;   // ebar[0..127] + gbar[128]
        return;
    }
    int idx = blockIdx.x*256 + threadIdx.x;   // b*512 + d
    int b = idx >> 9, d = idx & 511;
    const float* p = a + (size_t)b*L_*D_ + d;
    ushort_t* q = a_b + (size_t)b*L_*D_ + d;
    float s = 0.f;
    for (int l=0;l<L_;l++){ float v = p[(size_t)l*D_]; s += v; q[(size_t)l*D_] = f2b(v); }
    mc[idx] = s * (1.f/(float)L_);
}

__global__ void gather_emb(const int* __restrict__ captions, const float* __restrict__ embW,
                           ushort_t* __restrict__ xemb){
    int i = blockIdx.x;                 // t*B + b
    int t = i / B_, b = i - t*B_;
    int cap = captions[b*T_ + t];
    float4 v = ((const float4*)(embW + (size_t)cap*E_))[threadIdx.x];
    ushort_t r[4] = {f2b(v.x),f2b(v.y),f2b(v.z),f2b(v.w)};
    *(uint2*)(xemb + (size_t)i*E_ + threadIdx.x*4) = *(uint2*)r;
}

// h0: cvt to xcat + full hWp0 + zero hWp1;  grid B x 512
__global__ __launch_bounds__(512) void hw0cvt_k(const float* __restrict__ h0f,
                        const ushort_t* __restrict__ WhcT,
                        ushort_t* __restrict__ xcat, float* __restrict__ hWp){
    int b = blockIdx.x, tid = threadIdx.x;
    int lane = tid & 63, wave = tid >> 6;
    __shared__ ushort_t hls[512];
    float hv = h0f[b*H_ + tid];
    ushort_t hb = f2b(hv);
    xcat[(size_t)b*KCAT + D_ + tid] = hb;
    hls[tid] = hb;
    hWp[(size_t)(b*2+1)*512 + tid] = 0.f;
    __syncthreads();
    int wn = wave * 64;
    int col16 = lane & 15;
    int khi = (lane >> 4) * 8;
    bool a_on = (col16 == 0);
    f32x4 acc[4];
    #pragma unroll
    for (int f=0;f<4;f++) acc[f] = (f32x4){0.f,0.f,0.f,0.f};
    for (int kk=0; kk<16; kk++){
        bf16x8 af = (bf16x8){0,0,0,0,0,0,0,0};
        if (a_on) af = *(const bf16x8*)&hls[kk*32 + khi];
        #pragma unroll
        for (int f=0;f<4;f++){
            bf16x8 bf = *(const bf16x8*)(WhcT + (size_t)(wn + f*16 + col16)*512 + kk*32 + khi);
            acc[f] = __builtin_amdgcn_mfma_f32_16x16x32_bf16(af, bf, acc[f], 0, 0, 0);
        }
    }
    if (lane < 16){
        #pragma unroll
        for (int f=0;f<4;f++) hWp[(size_t)(b*2+0)*512 + wn + f*16 + lane] = acc[f][0];
    }
}

// ================= persistent cooperative loop: r7 phases verbatim =================
struct LoopArgs {
    const ushort_t* wa;
    const ushort_t* a_b;
    const float* v;
    const float* beta_W;
    const float* beta_b;
    const ushort_t* WhcT;
    const ushort_t* WcatT;
    const float* embWih;
    float* cbuf;
    float* hWp;
    ushort_t* xcat;
    ushort_t* Hall;
    float* alphas;
    float* ebuf;
    float* gp;
    unsigned* ebar;   // [128]
    unsigned* gbar;   // [1]
};

__device__ __forceinline__ void spin_sync(unsigned* ctr, unsigned tgt){
    __syncthreads();
    if (threadIdx.x == 0){
        __threadfence();
        atomicAdd(ctr, 1u);
        while (__hip_atomic_load(ctr, __ATOMIC_ACQUIRE, __HIP_MEMORY_SCOPE_AGENT) < tgt)
            __builtin_amdgcn_s_sleep(1);
    }
    __syncthreads();
}

__global__ __launch_bounds__(512) void loop2_k(LoopArgs p){
    const int blk = blockIdx.x;       // 0..255
    const int b = blk >> 1, half = blk & 1;
    const int tid = threadIdx.x;
    const int lane = tid & 63, wave = tid >> 6;
    __shared__ ushort_t hls[256];
    __shared__ float red[512];
    __shared__ float al_s[224];
    __shared__ float part[2][256];
    __shared__ ushort_t As[128*32];
    __shared__ ushort_t Bs[64*32];
    unsigned gtgt = 0;

    for (int t = 0; t < TM1; ++t){
        // ===== phase L: lstm(t-1) own j-half + hW K-partial (skip at t==0) =====
        if (t > 0){
            if (tid < 256){
                const int j = half*256 + tid;
                const float* eb = p.embWih + ((size_t)((t-1)*B_ + b))*G4H;
                float gi = eb[j], gf = eb[H_+j], gg = eb[2*H_+j], go = eb[3*H_+j];
                #pragma unroll
                for (int ks=0; ks<8; ks++){
                    const float* g = p.gp + ((size_t)(ks*B_ + b))*G4H;
                    gi += g[j]; gf += g[H_+j]; gg += g[2*H_+j]; go += g[3*H_+j];
                }
                float ig = sigmoidf_(gi), fg = sigmoidf_(gf);
                float g2 = fast_tanh(gg), og = sigmoidf_(go);
                float c = fg*p.cbuf[b*H_+j] + ig*g2;
                float h = og*fast_tanh(c);
                p.cbuf[b*H_+j] = c;
                ushort_t hb = f2b(h);
                p.xcat[(size_t)b*KCAT + D_ + j] = hb;
                p.Hall[((size_t)(t-1)*B_ + b)*H_ + j] = hb;
                hls[tid] = hb;
            }
            __syncthreads();
            int wn = wave * 64;
            int col16 = lane & 15;
            int khi = (lane >> 4) * 8;
            bool a_on = (col16 == 0);
            f32x4 acc[4];
            #pragma unroll
            for (int f=0;f<4;f++) acc[f] = (f32x4){0.f,0.f,0.f,0.f};
            #pragma unroll
            for (int kk=0; kk<8; kk++){
                bf16x8 af = (bf16x8){0,0,0,0,0,0,0,0};
                if (a_on) af = *(const bf16x8*)&hls[kk*32 + khi];
                #pragma unroll
                for (int f=0;f<4;f++){
                    bf16x8 bf = *(const bf16x8*)(p.WhcT + (size_t)(wn + f*16 + col16)*512 + half*256 + kk*32 + khi);
                    acc[f] = __builtin_amdgcn_mfma_f32_16x16x32_bf16(af, bf, acc[f], 0, 0, 0);
                }
            }
            if (lane < 16){
                #pragma unroll
                for (int f=0;f<4;f++) p.hWp[(size_t)(b*2+half)*512 + wn + f*16 + lane] = acc[f][0];
            }
        }
        // ---- pair sync 1 ----
        spin_sync(&p.ebar[b], 4u*(unsigned)t + 2u);
        // ===== phase E: e over own l-half =====
        {
            const float* hp0 = p.hWp + (size_t)(b*2+0)*512 + lane*8;
            const float* hp1 = p.hWp + (size_t)(b*2+1)*512 + lane*8;
            float4 p00 = *(const float4*)hp0, p01 = *(const float4*)(hp0+4);
            float4 p10 = *(const float4*)hp1, p11 = *(const float4*)(hp1+4);
            float4 hw0 = make_float4(p00.x+p10.x, p00.y+p10.y, p00.z+p10.z, p00.w+p10.w);
            float4 hw1 = make_float4(p01.x+p11.x, p01.y+p11.y, p01.z+p11.z, p01.w+p11.w);
            const float* vp = p.v + lane*8;
            float4 v0 = *(const float4*)vp, v1 = *(const float4*)(vp+4);
            const int l0 = half*LH;
            for (int r = wave; r < LH; r += 8){
                int4 raw = *(const int4*)(p.wa + (((size_t)(b*L_ + l0 + r))<<9) + lane*8);
                const unsigned* u = (const unsigned*)&raw;
                float s;
                s  = fast_tanh(b2f_lo(u[0]) + hw0.x)*v0.x;
                s += fast_tanh(b2f_hi(u[0]) + hw0.y)*v0.y;
                s += fast_tanh(b2f_lo(u[1]) + hw0.z)*v0.z;
                s += fast_tanh(b2f_hi(u[1]) + hw0.w)*v0.w;
                s += fast_tanh(b2f_lo(u[2]) + hw1.x)*v1.x;
                s += fast_tanh(b2f_hi(u[2]) + hw1.y)*v1.y;
                s += fast_tanh(b2f_lo(u[3]) + hw1.z)*v1.z;
                s += fast_tanh(b2f_hi(u[3]) + hw1.w)*v1.w;
                #pragma unroll
                for (int off=32; off; off>>=1) s += __shfl_down(s, off);
                if (lane==0) p.ebuf[b*L_ + l0 + r] = s;
            }
        }
        // ---- pair sync 2 ----
        spin_sync(&p.ebar[b], 4u*(unsigned)t + 4u);
        // ===== softmax + beta + ctx =====
        {
            float ev = (tid < L_) ? p.ebuf[b*L_ + tid] : -3.0e38f;
            red[tid] = ev; __syncthreads();
            #pragma unroll
            for (int s=256; s; s>>=1){ if (tid<s) red[tid] = fmaxf(red[tid], red[tid+s]); __syncthreads(); }
            float m = red[0]; __syncthreads();
            float pr = (tid < L_) ? __expf(ev - m) : 0.f;
            red[tid] = pr; __syncthreads();
            #pragma unroll
            for (int s=256; s; s>>=1){ if (tid<s) red[tid] += red[tid+s]; __syncthreads(); }
            float inv = 1.f / red[0];
            __syncthreads();
            if (tid < L_) al_s[tid] = pr*inv;
            const int l0 = half*LH;
            if (tid >= l0 && tid < l0 + LH)
                __builtin_nontemporal_store(pr*inv, p.alphas + (size_t)b*TM1*L_ + (size_t)t*L_ + tid);
            float dv = b2f(p.xcat[(size_t)b*KCAT + D_ + tid]) * p.beta_W[tid];
            red[tid] = dv; __syncthreads();
            #pragma unroll
            for (int s=256; s; s>>=1){ if (tid<s) red[tid] += red[tid+s]; __syncthreads(); }
            float beta = sigmoidf_(red[0] + p.beta_b[0]);
            __syncthreads();
            const int d  = half*256 + (tid & 255);
            const int lr = tid >> 8;
            const ushort_t* pa = p.a_b + (((size_t)(b*L_ + lr*LH))<<9) + d;
            float s0 = 0.f;
            #pragma unroll 7
            for (int i=0; i<LH; ++i) s0 = fmaf(al_s[lr*LH + i], b2f(pa[(size_t)i*512]), s0);
            part[lr][tid & 255] = s0;
            __syncthreads();
            if (tid < 256)
                p.xcat[(size_t)b*KCAT + half*256 + tid] = f2b(beta*(part[0][tid] + part[1][tid]));
        }
        // ---- grid sync A: ctx/h visible to all ----
        gtgt += NBLK; spin_sync(p.gbar, gtgt);
        // ===== phase G: gates partials; block = (bn = blk&31, ks = blk>>5) =====
        {
            const int bn = (blk & 31) * 64;
            const int ks = blk >> 5;
            const int wm = (wave & 3) * 32;
            const int wn = (wave >> 2) * 32;
            const int lrow = lane & 15, lk8 = (lane >> 4) * 8;
            const int ra = tid >> 2, kqa = (tid & 3)*8;
            f32x4 acc[2][2];
            #pragma unroll
            for (int i=0;i<2;i++)
                #pragma unroll
                for (int j=0;j<2;j++) acc[i][j] = (f32x4){0.f,0.f,0.f,0.f};
            #pragma unroll
            for (int kk = 0; kk < 4; ++kk){
                int k0 = ks*128 + kk*32;
                int4 av = *(const int4*)(p.xcat + (size_t)ra*KCAT + k0 + kqa);
                int4 bv;
                if (tid < 256) bv = *(const int4*)(p.WcatT + (size_t)(bn + ra)*KCAT + k0 + kqa);
                __syncthreads();
                *(int4*)&As[ra*32 + kqa] = av;
                if (tid < 256) *(int4*)&Bs[ra*32 + kqa] = bv;
                __syncthreads();
                bf16x8 af[2], bfr[2];
                #pragma unroll
                for (int i=0;i<2;i++) af[i]  = *(bf16x8*)&As[(wm + i*16 + lrow)*32 + lk8];
                #pragma unroll
                for (int j=0;j<2;j++) bfr[j] = *(bf16x8*)&Bs[(wn + j*16 + lrow)*32 + lk8];
                #pragma unroll
                for (int i=0;i<2;i++)
                    #pragma unroll
                    for (int j=0;j<2;j++)
                        acc[i][j] = __builtin_amdgcn_mfma_f32_16x16x32_bf16(af[i], bfr[j], acc[i][j], 0, 0, 0);
            }
            const int rq = (lane >> 4) * 4;
            #pragma unroll
            for (int i=0;i<2;i++)
                #pragma unroll
                for (int j=0;j<2;j++){
                    int gcol = bn + wn + j*16 + lrow;
                    #pragma unroll
                    for (int q=0;q<4;q++){
                        int grow = wm + i*16 + rq + q;
                        p.gp[((size_t)(ks*B_ + grow))*G4H + gcol] = acc[i][j][q];
                    }
                }
        }
        // ---- grid sync B: gp visible to all ----
        gtgt += NBLK; spin_sync(p.gbar, gtgt);
    }
    // ===== final lstm: h_19 -> Hall[18] =====
    if (tid < 256){
        const int j = half*256 + tid;
        const float* eb = p.embWih + ((size_t)(18*B_ + b))*G4H;
        float gi = eb[j], gf = eb[H_+j], gg = eb[2*H_+j], go = eb[3*H_+j];
        #pragma unroll
        for (int ks=0; ks<8; ks++){
            const float* g = p.gp + ((size_t)(ks*B_ + b))*G4H;
            gi += g[j]; gf += g[H_+j]; gg += g[2*H_+j]; go += g[3*H_+j];
        }
        float ig = sigmoidf_(gi), fg = sigmoidf_(gf);
        float g2 = fast_tanh(gg), og = sigmoidf_(go);
        float c = fg*p.cbuf[b*H_+j] + ig*g2;
        float h = og*fast_tanh(c);
        p.Hall[((size_t)18*B_ + b)*H_ + j] = f2b(h);
    }
}

extern "C" void kernel_launch(void* const* d_in, const int* in_sizes, int n_in,
                              void* d_out, int out_size, void* d_ws, size_t ws_size,
                              hipStream_t stream) {
    const float* a      = (const float*)d_in[0];
    const int*   caps   = (const int*)  d_in[1];
    const float* embW   = (const float*)d_in[3];
    const float* Wa     = (const float*)d_in[4];
    const float* Wh     = (const float*)d_in[5];
    const float* Wc     = (const float*)d_in[6];
    const float* v      = (const float*)d_in[7];
    const float* beta_W = (const float*)d_in[8];
    const float* beta_b = (const float*)d_in[9];
    const float* W_ih   = (const float*)d_in[10];
    const float* W_hh   = (const float*)d_in[11];
    const float* b_ih   = (const float*)d_in[12];
    const float* b_hh   = (const float*)d_in[13];
    const float* fc_W   = (const float*)d_in[14];
    const float* fc_b   = (const float*)d_in[15];
    const float* iWh    = (const float*)d_in[16];
    const float* ibh    = (const float*)d_in[17];
    const float* iWc    = (const float*)d_in[18];
    const float* ibc    = (const float*)d_in[19];

    float* out    = (float*)d_out;
    float* alphas = out + (size_t)ROWS*V_;

    // d_out scratch (dead before final logits GEMM overwrites it)
    char* ob = (char*)d_out;
    ushort_t* wa_b   = (ushort_t*)(ob);               // 25,690,112 B
    ushort_t* a_b    = (ushort_t*)(ob + 25690112);    // 25,690,112 B
    float*    embWih = (float*)   (ob + 51380224);    // 19,922,944 B

    // d_ws layout (byte offsets)
    char* wb = (char*)d_ws;
    float* mean_ctx = (float*)(wb);                 // 262144
    float* cbuf     = (float*)(wb + 262144);        // 262144
    float* h0f      = (float*)(wb + 524288);        // 262144
    float* hWp      = (float*)(wb + 786432);        // 524288
    float* ebuf     = (float*)(wb + 1310720);       // 102400
    float* bias4h   = (float*)(wb + 1413120);       // 8192
    unsigned* bars  = (unsigned*)(wb + 1421312);    // 1024: ebar[0..127], gbar = bars+128
    float* gp       = (float*)(wb + 1422336);       // 8388608
    ushort_t* xcat_b = (ushort_t*)(wb + 9810944);   // 262144
    ushort_t* xemb_b = (ushort_t*)(wb + 10073088);  // 1245184
    ushort_t* Hall   = (ushort_t*)(wb + 11318272);  // 2490368
    ushort_t* WaT    = (ushort_t*)(wb + 13808640);  // 524288
    ushort_t* WhcT   = (ushort_t*)(wb + 14332928);  // 524288
    ushort_t* WihT   = (ushort_t*)(wb + 14857216);  // 1048576
    ushort_t* WcatT  = (ushort_t*)(wb + 15905792);  // 4194304
    ushort_t* fcWT   = (ushort_t*)(wb + 20100096);  // 10354688 -> ends ~29.0MB

    // ---- prep ----
    TJobs J;
    J.j[0] = { Wa,   nullptr, WaT,  512, 512, 512,  0,   512,  16, 256 };
    J.j[1] = { Wh,   Wc,      WhcT, 512, 512, 512,  0,   512,  16, 256 };
    J.j[2] = { W_ih, nullptr, WihT, G4H, 256, G4H,  0,   256,  64, 512 };
    J.j[3] = { W_ih + (size_t)E_*G4H, nullptr, WcatT, G4H, 512, G4H, 0,   KCAT, 64, 1024 };
    J.j[4] = { W_hh, nullptr, WcatT, G4H, 512, G4H,  512, KCAT, 64, 1024 };
    J.j[5] = { fc_W, nullptr, fcWT, V_,  512, V_,   0,   512,  316, 5056 };
    combo_trans_k<<<8128, 256, 0, stream>>>(J);
    mean_cvt_k<<<257, 256, 0, stream>>>(a, a_b, mean_ctx, b_ih, b_hh, bias4h, bars);
    gather_emb<<<ROWS, 64, 0, stream>>>(caps, embW, xemb_b);
    gemm64t2<<<dim3(8,2,2), 256, 0, stream>>>(mean_ctx, D_, iWh, iWc, H_, h0f, cbuf, H_, ibh, ibc);
    hw0cvt_k<<<B_, 512, 0, stream>>>(h0f, WhcT, xcat_b, hWp);
    // wa_b = bf16(a @ Wa)    (25088 x 512 x 512)
    gemm_mfma<1,0,0,0><<<dim3(4,196), 256, 0, stream>>>(a_b, D_, WaT, D_, wa_b, A_, A_, D_, nullptr);
    // embWih = xemb @ W_ih[:E] + (b_ih+b_hh)   (2432 x 2048 x 256)
    gemm_mfma<0,1,0,0><<<dim3(16,19), 256, 0, stream>>>(xemb_b, E_, WihT, E_, embWih, G4H, G4H, E_, bias4h);

    // ---- persistent 19-step loop (cooperative; r7 phases verbatim) ----
    LoopArgs la;
    la.wa = wa_b; la.a_b = a_b; la.v = v; la.beta_W = beta_W; la.beta_b = beta_b;
    la.WhcT = WhcT; la.WcatT = WcatT; la.embWih = embWih;
    la.cbuf = cbuf; la.hWp = hWp; la.xcat = xcat_b; la.Hall = Hall;
    la.alphas = alphas; la.ebuf = ebuf; la.gp = gp;
    la.ebar = bars; la.gbar = bars + 128;
    void* kargs[] = { &la };
    hipLaunchCooperativeKernel((const void*)loop2_k, dim3(NBLK), dim3(512), kargs, 0, stream);

    // logits = Hall @ fc_W + fc_b   (2432 x 10000 x 512), NT stores + XCD swizzle
    gemm_mfma<0,1,1,1><<<dim3(1520), 256, 0, stream>>>(Hall, H_, fcWT, H_, out, V_, V_, H_, fc_b);
}

// Round 9
// 1485.074 us; speedup vs baseline: 1.4825x; 1.4825x over previous
//
#include <hip/hip_runtime.h>
#include <hip/hip_bf16.h>
#include <math.h>

#define B_ 128
#define L_ 196
#define D_ 512
#define T_ 20
#define V_ 10000
#define E_ 256
#define H_ 512
#define A_ 512
#define TM1 19
#define ROWS (TM1*B_)      /* 2432 */
#define G4H 2048
#define KCAT 1024
#define LQ 49

typedef unsigned short ushort_t;
typedef __attribute__((ext_vector_type(8))) short bf16x8;
typedef __attribute__((ext_vector_type(4))) float f32x4;

__device__ __forceinline__ float fast_tanh(float x){
    float ax = fabsf(x);
    float e = __expf(-2.f*ax);
    float r = __builtin_amdgcn_rcpf(1.f + e);
    return copysignf((1.f - e)*r, x);
}
__device__ __forceinline__ float sigmoidf_(float x){
    return __builtin_amdgcn_rcpf(1.f + __expf(-x));
}
__device__ __forceinline__ ushort_t f2b(float f){
    union{float f; unsigned u;} x; x.f = f;
    unsigned r = x.u + 0x7fffu + ((x.u>>16)&1u);
    return (ushort_t)(r>>16);
}
__device__ __forceinline__ float b2f(ushort_t h){
    union{unsigned u; float f;} x; x.u = ((unsigned)h)<<16;
    return x.f;
}
__device__ __forceinline__ float b2f_lo(unsigned u){ union{unsigned u; float f;} x; x.u = u<<16; return x.f; }
__device__ __forceinline__ float b2f_hi(unsigned u){ union{unsigned u; float f;} x; x.u = u & 0xffff0000u; return x.f; }

// ================= bf16 MFMA GEMM: C = A @ BT^T (+bias), swizzled LDS =================
template<int OUT_BF16, int HAS_BIAS, int NT, int SWZ>
__global__ __launch_bounds__(256)
void gemm_mfma(const ushort_t* __restrict__ A, int lda,
               const ushort_t* __restrict__ BT, int ldb,
               void* __restrict__ Cout, int ldc,
               int N, int K, const float* __restrict__ bias)
{
    __shared__ ushort_t As[128*32];
    __shared__ ushort_t Bs[128*32];
    int bm, bn;
    if (SWZ){
        int bid = blockIdx.x;                 // 0..1519
        int swz = (bid & 7)*190 + (bid >> 3); // XCD-contiguous chunks
        int mt = swz % 19, nt = swz / 19;     // nt 0..79
        if (nt >= 79) return;
        bm = mt*128; bn = nt*128;
    } else {
        bm = blockIdx.y * 128; bn = blockIdx.x * 128;
    }
    const int tid = threadIdx.x;
    const int lane = tid & 63;
    const int wave = tid >> 6;
    const int wm = (wave >> 1) * 64;
    const int wn = (wave & 1) * 64;
    const int lrow = lane & 15;
    const int lk8  = (lane >> 4) * 8;
    const int srow = tid >> 2;
    const int skq  = ((tid & 3) * 8) ^ ((srow & 3) << 3);   // write-side swizzle
    const int skq0 = (tid & 3) * 8;

    f32x4 acc[4][4];
    #pragma unroll
    for (int i=0;i<4;i++)
        #pragma unroll
        for (int j=0;j<4;j++) acc[i][j] = (f32x4){0.f,0.f,0.f,0.f};

    const ushort_t* Abase = A  + (size_t)(bm+srow)*lda + skq0;
    const ushort_t* Bbase = BT + (size_t)(bn+srow)*ldb + skq0;

    for (int k0 = 0; k0 < K; k0 += 32) {
        int4 a0 = *(const int4*)(Abase + k0);
        int4 a1 = *(const int4*)(Abase + (size_t)64*lda + k0);
        int4 b0 = *(const int4*)(Bbase + k0);
        int4 b1 = *(const int4*)(Bbase + (size_t)64*ldb + k0);
        __syncthreads();
        *(int4*)&As[srow*32 + skq]      = a0;
        *(int4*)&As[(srow+64)*32 + skq] = a1;
        *(int4*)&Bs[srow*32 + skq]      = b0;
        *(int4*)&Bs[(srow+64)*32 + skq] = b1;
        __syncthreads();
        bf16x8 af[4], bfr[4];
        #pragma unroll
        for (int i=0;i<4;i++){
            int r = wm + i*16 + lrow;
            af[i]  = *(bf16x8*)&As[r*32 + (lk8 ^ ((r & 3) << 3))];
        }
        #pragma unroll
        for (int j=0;j<4;j++){
            int r = wn + j*16 + lrow;
            bfr[j] = *(bf16x8*)&Bs[r*32 + (lk8 ^ ((r & 3) << 3))];
        }
        #pragma unroll
        for (int i=0;i<4;i++)
            #pragma unroll
            for (int j=0;j<4;j++)
                acc[i][j] = __builtin_amdgcn_mfma_f32_16x16x32_bf16(af[i], bfr[j], acc[i][j], 0, 0, 0);
    }

    const int rq = (lane >> 4) * 4;
    #pragma unroll
    for (int j=0;j<4;j++){
        int col = bn + wn + j*16 + lrow;
        if (col >= N) continue;
        float bv = HAS_BIAS ? bias[col] : 0.f;
        #pragma unroll
        for (int i=0;i<4;i++){
            #pragma unroll
            for (int q=0;q<4;q++){
                int row = bm + wm + i*16 + rq + q;
                float v = acc[i][j][q] + bv;
                if (OUT_BF16) ((ushort_t*)Cout)[(size_t)row*ldc + col] = f2b(v);
                else if (NT)  __builtin_nontemporal_store(v, &((float*)Cout)[(size_t)row*ldc + col]);
                else          ((float*)Cout)[(size_t)row*ldc + col] = v;
            }
        }
    }
}

// ============ f32 tile GEMM (init path): C = tanh(A@B + bias), z picks job ============
__global__ __launch_bounds__(256) void gemm64t2(const float* __restrict__ A, int lda,
                       const float* __restrict__ B0, const float* __restrict__ B1, int ldb,
                       float* __restrict__ C0, float* __restrict__ C1, int ldc,
                       const float* __restrict__ bias0, const float* __restrict__ bias1)
{
    const float* Bm  = blockIdx.z ? B1 : B0;
    float* C         = blockIdx.z ? C1 : C0;
    const float* bias= blockIdx.z ? bias1 : bias0;
    __shared__ float As[16][65];
    __shared__ float Bs[16][65];
    int bm = blockIdx.y*64, bn = blockIdx.x*64;
    int tid = threadIdx.x;
    int tx = tid & 15, ty = tid >> 4;
    float acc[4][4] = {};
    for (int k0 = 0; k0 < D_; k0 += 16) {
        {
            int r  = tid >> 2;
            int kq = (tid & 3) * 4;
            float4 va = *(const float4*)(A + (size_t)(bm+r)*lda + k0 + kq);
            As[kq+0][r]=va.x; As[kq+1][r]=va.y; As[kq+2][r]=va.z; As[kq+3][r]=va.w;
        }
        {
            int kk = tid >> 4;
            int nq = (tid & 15) * 4;
            float4 vb = *(const float4*)(Bm + (size_t)(k0+kk)*ldb + bn + nq);
            Bs[kk][nq+0]=vb.x; Bs[kk][nq+1]=vb.y; Bs[kk][nq+2]=vb.z; Bs[kk][nq+3]=vb.w;
        }
        __syncthreads();
        #pragma unroll
        for (int k = 0; k < 16; ++k) {
            float a0[4], b0[4];
            #pragma unroll
            for (int i=0;i<4;i++) a0[i] = As[k][ty*4+i];
            #pragma unroll
            for (int j=0;j<4;j++) b0[j] = Bs[k][tx*4+j];
            #pragma unroll
            for (int i=0;i<4;i++)
                #pragma unroll
                for (int j=0;j<4;j++)
                    acc[i][j] = fmaf(a0[i], b0[j], acc[i][j]);
        }
        __syncthreads();
    }
    #pragma unroll
    for (int i=0;i<4;i++){
        int row = bm + ty*4 + i;
        #pragma unroll
        for (int j=0;j<4;j++){
            int col = bn + tx*4 + j;
            C[(size_t)row*ldc + col] = fast_tanh(acc[i][j] + bias[col]);
        }
    }
}

// ================= combined transpose+cvt (all weights in one launch) =================
struct TJob { const float* src; const float* src2; ushort_t* dst;
              int lds, Ksz, Nsz, koff, ldk, nx, nblk; };
struct TJobs { TJob j[6]; };

__global__ __launch_bounds__(256) void combo_trans_k(TJobs J){
    __shared__ float t[32][33];
    int bid = blockIdx.x;
    int ji = 0;
    while (bid >= J.j[ji].nblk){ bid -= J.j[ji].nblk; ji++; }
    const TJob jb = J.j[ji];
    int n0 = (bid % jb.nx)*32, k0 = (bid / jb.nx)*32;
    int tx = threadIdx.x & 31, ty = threadIdx.x >> 5;
    #pragma unroll
    for (int kk = ty; kk < 32; kk += 8){
        int k = k0 + kk, n = n0 + tx;
        float v = 0.f;
        if (k < jb.Ksz && n < jb.Nsz){
            v = jb.src[(size_t)k*jb.lds + n];
            if (jb.src2) v += jb.src2[(size_t)k*jb.lds + n];
        }
        t[kk][tx] = v;
    }
    __syncthreads();
    #pragma unroll
    for (int nn = ty; nn < 32; nn += 8){
        int n = n0 + nn, k = k0 + tx;
        if (k < jb.Ksz) jb.dst[(size_t)n*jb.ldk + jb.koff + k] = f2b(t[tx][nn]);
    }
}

// vectorized: one pass over a (float4/lane): column means + bf16 copy; block 64 does bias4h + bars
__global__ __launch_bounds__(256) void mean_cvt_k(const float* __restrict__ a, ushort_t* __restrict__ a_b,
                                                  float* __restrict__ mc,
                                                  const float* __restrict__ b_ih, const float* __restrict__ b_hh,
                                                  float* __restrict__ bias4h, unsigned* __restrict__ bars){
    if (blockIdx.x == 64){
        for (int k = threadIdx.x; k < G4H; k += 256) bias4h[k] = b_ih[k] + b_hh[k];
        if (threadIdx.x < B_) bars[threadIdx.x] = 0u;
        return;
    }
    int idx = blockIdx.x*256 + threadIdx.x;   // b*128 + dq
    int b = idx >> 7, dq = (idx & 127) * 4;
    const float* p = a + (size_t)b*L_*D_ + dq;
    ushort_t* q = a_b + (size_t)b*L_*D_ + dq;
    float4 s = make_float4(0.f,0.f,0.f,0.f);
    for (int l=0;l<L_;l++){
        float4 v = *(const float4*)(p + (size_t)l*D_);
        s.x += v.x; s.y += v.y; s.z += v.z; s.w += v.w;
        ushort_t r[4] = {f2b(v.x),f2b(v.y),f2b(v.z),f2b(v.w)};
        *(uint2*)(q + (size_t)l*D_) = *(uint2*)r;
    }
    const float inv = 1.f/(float)L_;
    float4 o = make_float4(s.x*inv, s.y*inv, s.z*inv, s.w*inv);
    *(float4*)(mc + (size_t)b*D_ + dq) = o;
}

// 4 rows per block
__global__ __launch_bounds__(256) void gather_emb(const int* __restrict__ captions, const float* __restrict__ embW,
                           ushort_t* __restrict__ xemb){
    int i = blockIdx.x*4 + (threadIdx.x >> 6);    // t*B + b
    int lane = threadIdx.x & 63;
    int t = i / B_, b = i - t*B_;
    int cap = captions[b*T_ + t];
    float4 v = ((const float4*)(embW + (size_t)cap*E_))[lane];
    ushort_t r[4] = {f2b(v.x),f2b(v.y),f2b(v.z),f2b(v.w)};
    *(uint2*)(xemb + (size_t)i*E_ + lane*4) = *(uint2*)r;
}

// h0: cvt to xcat + full hW into partial 0; zero partials 1..3; grid B x 512
__global__ __launch_bounds__(512) void hw0cvt_k(const float* __restrict__ h0f,
                        const ushort_t* __restrict__ WhcT,
                        ushort_t* __restrict__ xcat, float* __restrict__ hWp){
    int b = blockIdx.x, tid = threadIdx.x;
    int lane = tid & 63, wave = tid >> 6;
    __shared__ ushort_t hls[512];
    float hv = h0f[b*H_ + tid];
    ushort_t hb = f2b(hv);
    xcat[(size_t)b*KCAT + D_ + tid] = hb;
    hls[tid] = hb;
    hWp[(size_t)(b*4+1)*512 + tid] = 0.f;
    hWp[(size_t)(b*4+2)*512 + tid] = 0.f;
    hWp[(size_t)(b*4+3)*512 + tid] = 0.f;
    __syncthreads();
    int wn = wave * 64;
    int col16 = lane & 15;
    int khi = (lane >> 4) * 8;
    bool a_on = (col16 == 0);
    f32x4 acc[4];
    #pragma unroll
    for (int f=0;f<4;f++) acc[f] = (f32x4){0.f,0.f,0.f,0.f};
    for (int kk=0; kk<16; kk++){
        bf16x8 af = (bf16x8){0,0,0,0,0,0,0,0};
        if (a_on) af = *(const bf16x8*)&hls[kk*32 + khi];
        #pragma unroll
        for (int f=0;f<4;f++){
            bf16x8 bf = *(const bf16x8*)(WhcT + (size_t)(wn + f*16 + col16)*512 + kk*32 + khi);
            acc[f] = __builtin_amdgcn_mfma_f32_16x16x32_bf16(af, bf, acc[f], 0, 0, 0);
        }
    }
    if (lane < 16){
        #pragma unroll
        for (int f=0;f<4;f++) hWp[(size_t)(b*4+0)*512 + wn + f*16 + lane] = acc[f][0];
    }
}

__device__ __forceinline__ void spin_sync(unsigned* ctr, unsigned tgt){
    __syncthreads();
    if (threadIdx.x == 0){
        __threadfence();
        atomicAdd(ctr, 1u);
        while (__hip_atomic_load(ctr, __ATOMIC_ACQUIRE, __HIP_MEMORY_SCOPE_AGENT) < tgt)
            __builtin_amdgcn_s_sleep(1);
    }
    __syncthreads();
}

// ================= mega3: lstm(t-1) qslice + hW K-partial + attention(t) qslice =================
// grid (B_, 4) x 256; 2 quad-syncs per step via monotonic ebar[b]
__global__ __launch_bounds__(256) void mega3_k(const ushort_t* __restrict__ wa,
                        const ushort_t* __restrict__ a_b,
                        const float* __restrict__ v,
                        const float* __restrict__ beta_W, const float* __restrict__ beta_b,
                        const ushort_t* __restrict__ WhcT,
                        const float* __restrict__ gp, const float* __restrict__ embWih,
                        float* __restrict__ cbuf, float* __restrict__ hWp,
                        ushort_t* __restrict__ xcat, ushort_t* __restrict__ Hall,
                        float* __restrict__ alphas_out, float* __restrict__ ebuf,
                        unsigned* __restrict__ ebar, int t)
{
    const int b = blockIdx.x, q = blockIdx.y;   // q in [0,4)
    const int tid = threadIdx.x;                // 0..255
    const int lane = tid & 63, wave = tid >> 6; // 4 waves
    __shared__ ushort_t hls[128];
    __shared__ float red[256];
    __shared__ float al_s[224];
    __shared__ float part[2][128];

    // ---- phase L: lstm(t-1) for own 128-j slice + hW K=128 partial (skip at t==0) ----
    if (t > 0){
        if (tid < 128){
            const int j = q*128 + tid;
            const float* eb = embWih + ((size_t)((t-1)*B_ + b))*G4H;
            float gi = eb[j], gf = eb[H_+j], gg = eb[2*H_+j], go = eb[3*H_+j];
            #pragma unroll
            for (int ks=0; ks<8; ks++){
                const float* g = gp + ((size_t)(ks*B_ + b))*G4H;
                gi += g[j]; gf += g[H_+j]; gg += g[2*H_+j]; go += g[3*H_+j];
            }
            float ig = sigmoidf_(gi), fg = sigmoidf_(gf);
            float g2 = fast_tanh(gg), og = sigmoidf_(go);
            float c = fg*cbuf[b*H_+j] + ig*g2;
            float h = og*fast_tanh(c);
            cbuf[b*H_+j] = c;
            ushort_t hb = f2b(h);
            xcat[(size_t)b*KCAT + D_ + j] = hb;
            Hall[((size_t)(t-1)*B_ + b)*H_ + j] = hb;
            hls[tid] = hb;
        }
        __syncthreads();
        // hWp[q] = h_slice @ Whc[q*128 .. q*128+128, :]
        const int col16 = lane & 15;
        const int khi = (lane >> 4) * 8;
        const bool a_on = (col16 == 0);
        f32x4 acc[8];
        #pragma unroll
        for (int f=0;f<8;f++) acc[f] = (f32x4){0.f,0.f,0.f,0.f};
        #pragma unroll
        for (int kk=0; kk<4; kk++){
            bf16x8 af = (bf16x8){0,0,0,0,0,0,0,0};
            if (a_on) af = *(const bf16x8*)&hls[kk*32 + khi];
            #pragma unroll
            for (int f=0;f<8;f++){
                int col = wave*128 + f*16 + col16;
                bf16x8 bf = *(const bf16x8*)(WhcT + (size_t)col*512 + q*128 + kk*32 + khi);
                acc[f] = __builtin_amdgcn_mfma_f32_16x16x32_bf16(af, bf, acc[f], 0, 0, 0);
            }
        }
        if (lane < 16){
            #pragma unroll
            for (int f=0;f<8;f++)
                hWp[(size_t)(b*4+q)*512 + wave*128 + f*16 + lane] = acc[f][0];
        }
    }
    // ---- quad sync 1: h + hWp complete for all 4 slices ----
    spin_sync(&ebar[b], 8u*(unsigned)t + 4u);
    // ---- phase E: e over own 49-l slice ----
    {
        float4 hw0 = make_float4(0.f,0.f,0.f,0.f), hw1 = make_float4(0.f,0.f,0.f,0.f);
        #pragma unroll
        for (int qq=0; qq<4; qq++){
            const float* hp = hWp + (size_t)(b*4+qq)*512 + lane*8;
            float4 x0 = *(const float4*)hp, x1 = *(const float4*)(hp+4);
            hw0.x += x0.x; hw0.y += x0.y; hw0.z += x0.z; hw0.w += x0.w;
            hw1.x += x1.x; hw1.y += x1.y; hw1.z += x1.z; hw1.w += x1.w;
        }
        const float* vp = v + lane*8;
        float4 v0 = *(const float4*)vp, v1 = *(const float4*)(vp+4);
        const int l0 = q*LQ;
        for (int r = wave; r < LQ; r += 4){
            int4 raw = *(const int4*)(wa + (((size_t)(b*L_ + l0 + r))<<9) + lane*8);
            const unsigned* u = (const unsigned*)&raw;
            float s;
            s  = fast_tanh(b2f_lo(u[0]) + hw0.x)*v0.x;
            s += fast_tanh(b2f_hi(u[0]) + hw0.y)*v0.y;
            s += fast_tanh(b2f_lo(u[1]) + hw0.z)*v0.z;
            s += fast_tanh(b2f_hi(u[1]) + hw0.w)*v0.w;
            s += fast_tanh(b2f_lo(u[2]) + hw1.x)*v1.x;
            s += fast_tanh(b2f_hi(u[2]) + hw1.y)*v1.y;
            s += fast_tanh(b2f_lo(u[3]) + hw1.z)*v1.z;
            s += fast_tanh(b2f_hi(u[3]) + hw1.w)*v1.w;
            #pragma unroll
            for (int off=32; off; off>>=1) s += __shfl_down(s, off);
            if (lane==0) ebuf[b*L_ + l0 + r] = s;
        }
    }
    // ---- quad sync 2: e complete ----
    spin_sync(&ebar[b], 8u*(unsigned)t + 8u);
    // ---- softmax over 196 (redundant per quarter) ----
    float ev = (tid < L_) ? ebuf[b*L_ + tid] : -3.0e38f;
    red[tid] = ev; __syncthreads();
    #pragma unroll
    for (int s=128; s; s>>=1){ if (tid<s) red[tid] = fmaxf(red[tid], red[tid+s]); __syncthreads(); }
    float m = red[0]; __syncthreads();
    float pr = (tid < L_) ? __expf(ev - m) : 0.f;
    red[tid] = pr; __syncthreads();
    #pragma unroll
    for (int s=128; s; s>>=1){ if (tid<s) red[tid] += red[tid+s]; __syncthreads(); }
    float inv = 1.f / red[0];
    __syncthreads();
    if (tid < L_) al_s[tid] = pr*inv;
    if (tid >= q*LQ && tid < q*LQ + LQ)
        __builtin_nontemporal_store(pr*inv, alphas_out + (size_t)b*TM1*L_ + (size_t)t*L_ + tid);
    // ---- beta: h . beta_W (2 elems per thread) ----
    {
        const ushort_t* hb = xcat + (size_t)b*KCAT + D_;
        float dv = b2f(hb[tid])*beta_W[tid] + b2f(hb[tid+256])*beta_W[tid+256];
        red[tid] = dv;
    }
    __syncthreads();
    #pragma unroll
    for (int s=128; s; s>>=1){ if (tid<s) red[tid] += red[tid+s]; __syncthreads(); }
    float beta = sigmoidf_(red[0] + beta_b[0]);
    __syncthreads();
    // ---- ctx: own 128-d slice, l split in halves by tid>>7 ----
    const int d  = q*128 + (tid & 127);
    const int lr = tid >> 7;
    const ushort_t* pa = a_b + (((size_t)(b*L_ + lr*98))<<9) + d;
    float s0 = 0.f;
    #pragma unroll 7
    for (int i=0; i<98; ++i) s0 = fmaf(al_s[lr*98 + i], b2f(pa[(size_t)i*512]), s0);
    part[lr][tid & 127] = s0;
    __syncthreads();
    if (tid < 128)
        xcat[(size_t)b*KCAT + q*128 + tid] = f2b(beta*(part[0][tid] + part[1][tid]));
}

// gates partials: grid (32, 8) x 256; tile M128 x N64, K-chunk 128
__global__ __launch_bounds__(256) void gates_k(const ushort_t* __restrict__ xcat,
                        const ushort_t* __restrict__ WcatT, float* __restrict__ gp){
    __shared__ ushort_t As[128*32];
    __shared__ ushort_t Bs[64*32];
    const int bn = blockIdx.x*64;
    const int ks = blockIdx.y;
    const int tid = threadIdx.x;
    const int lane = tid & 63, wave = tid >> 6;
    const int wm = wave*32;
    const int lrow = lane & 15;
    const int lk8 = (lane >> 4) * 8;
    f32x4 acc[2][4];
    #pragma unroll
    for (int i=0;i<2;i++)
        #pragma unroll
        for (int j=0;j<4;j++) acc[i][j] = (f32x4){0.f,0.f,0.f,0.f};

    for (int kk = 0; kk < 4; ++kk){
        int k0 = ks*128 + kk*32;
        int c0 = 2*tid;
        int r0 = c0 >> 2,  kq0 = (c0 & 3)*8;
        int r1 = (c0+1) >> 2, kq1 = ((c0+1) & 3)*8;
        int4 a0 = *(const int4*)(xcat + (size_t)r0*KCAT + k0 + kq0);
        int4 a1 = *(const int4*)(xcat + (size_t)r1*KCAT + k0 + kq1);
        int rb = tid >> 2, kqb = (tid & 3)*8;
        int4 b0 = *(const int4*)(WcatT + (size_t)(bn+rb)*KCAT + k0 + kqb);
        __syncthreads();
        *(int4*)&As[r0*32 + kq0] = a0;
        *(int4*)&As[r1*32 + kq1] = a1;
        *(int4*)&Bs[rb*32 + kqb] = b0;
        __syncthreads();
        bf16x8 af[2], bfr[4];
        #pragma unroll
        for (int i=0;i<2;i++) af[i] = *(bf16x8*)&As[(wm + i*16 + lrow)*32 + lk8];
        #pragma unroll
        for (int j=0;j<4;j++) bfr[j] = *(bf16x8*)&Bs[(j*16 + lrow)*32 + lk8];
        #pragma unroll
        for (int i=0;i<2;i++)
            #pragma unroll
            for (int j=0;j<4;j++)
                acc[i][j] = __builtin_amdgcn_mfma_f32_16x16x32_bf16(af[i], bfr[j], acc[i][j], 0, 0, 0);
    }
    const int rq = (lane >> 4) * 4;
    #pragma unroll
    for (int i=0;i<2;i++){
        #pragma unroll
        for (int j=0;j<4;j++){
            int gcol = bn + j*16 + lrow;
            #pragma unroll
            for (int q=0;q<4;q++){
                int grow = wm + i*16 + rq + q;
                gp[((size_t)(ks*B_ + grow))*G4H + gcol] = acc[i][j][q];
            }
        }
    }
}

// final lstm (h_19 -> Hall[18]); grid B x 512
__global__ __launch_bounds__(512) void lstmfin_k(const float* __restrict__ gp, const float* __restrict__ embWih,
                       const float* __restrict__ cbuf, ushort_t* __restrict__ Hall){
    int b = blockIdx.x, j = threadIdx.x;
    const float* eb = embWih + ((size_t)(18*B_ + b))*G4H;
    float gi = eb[j], gf = eb[H_+j], gg = eb[2*H_+j], go = eb[3*H_+j];
    #pragma unroll
    for (int ks=0; ks<8; ks++){
        const float* g = gp + ((size_t)(ks*B_ + b))*G4H;
        gi += g[j]; gf += g[H_+j]; gg += g[2*H_+j]; go += g[3*H_+j];
    }
    float ig = sigmoidf_(gi), fg = sigmoidf_(gf);
    float g2 = fast_tanh(gg), og = sigmoidf_(go);
    float c = fg*cbuf[b*H_+j] + ig*g2;
    float h = og*fast_tanh(c);
    Hall[((size_t)18*B_ + b)*H_ + j] = f2b(h);
}

extern "C" void kernel_launch(void* const* d_in, const int* in_sizes, int n_in,
                              void* d_out, int out_size, void* d_ws, size_t ws_size,
                              hipStream_t stream) {
    const float* a      = (const float*)d_in[0];
    const int*   caps   = (const int*)  d_in[1];
    const float* embW   = (const float*)d_in[3];
    const float* Wa     = (const float*)d_in[4];
    const float* Wh     = (const float*)d_in[5];
    const float* Wc     = (const float*)d_in[6];
    const float* v      = (const float*)d_in[7];
    const float* beta_W = (const float*)d_in[8];
    const float* beta_b = (const float*)d_in[9];
    const float* W_ih   = (const float*)d_in[10];
    const float* W_hh   = (const float*)d_in[11];
    const float* b_ih   = (const float*)d_in[12];
    const float* b_hh   = (const float*)d_in[13];
    const float* fc_W   = (const float*)d_in[14];
    const float* fc_b   = (const float*)d_in[15];
    const float* iWh    = (const float*)d_in[16];
    const float* ibh    = (const float*)d_in[17];
    const float* iWc    = (const float*)d_in[18];
    const float* ibc    = (const float*)d_in[19];

    float* out    = (float*)d_out;
    float* alphas = out + (size_t)ROWS*V_;

    // d_out scratch (dead before final logits GEMM overwrites it)
    char* ob = (char*)d_out;
    ushort_t* wa_b   = (ushort_t*)(ob);               // 25,690,112 B
    ushort_t* a_b    = (ushort_t*)(ob + 25690112);    // 25,690,112 B
    float*    embWih = (float*)   (ob + 51380224);    // 19,922,944 B

    // d_ws layout (byte offsets)
    char* wb = (char*)d_ws;
    float* mean_ctx = (float*)(wb);                 // 262144
    float* cbuf     = (float*)(wb + 262144);        // 262144
    float* h0f      = (float*)(wb + 524288);        // 262144
    float* hWp      = (float*)(wb + 786432);        // 1048576 (128*4*512 f32)
    float* ebuf     = (float*)(wb + 1835008);       // 102400
    float* bias4h   = (float*)(wb + 1937408);       // 8192
    unsigned* bars  = (unsigned*)(wb + 1945600);    // 1024: ebar[0..127]
    float* gp       = (float*)(wb + 1949696);       // 8388608
    ushort_t* xcat_b = (ushort_t*)(wb + 10338304);  // 262144
    ushort_t* xemb_b = (ushort_t*)(wb + 10600448);  // 1245184
    ushort_t* Hall   = (ushort_t*)(wb + 11845632);  // 2490368
    ushort_t* WaT    = (ushort_t*)(wb + 14336000);  // 524288
    ushort_t* WhcT   = (ushort_t*)(wb + 14860288);  // 524288
    ushort_t* WihT   = (ushort_t*)(wb + 15384576);  // 1048576
    ushort_t* WcatT  = (ushort_t*)(wb + 16433152);  // 4194304
    ushort_t* fcWT   = (ushort_t*)(wb + 20627456);  // 10354688 -> ends ~31.0MB

    // ---- prep ----
    TJobs J;
    J.j[0] = { Wa,   nullptr, WaT,  512, 512, 512,  0,   512,  16, 256 };
    J.j[1] = { Wh,   Wc,      WhcT, 512, 512, 512,  0,   512,  16, 256 };
    J.j[2] = { W_ih, nullptr, WihT, G4H, 256, G4H,  0,   256,  64, 512 };
    J.j[3] = { W_ih + (size_t)E_*G4H, nullptr, WcatT, G4H, 512, G4H, 0,   KCAT, 64, 1024 };
    J.j[4] = { W_hh, nullptr, WcatT, G4H, 512, G4H,  512, KCAT, 64, 1024 };
    J.j[5] = { fc_W, nullptr, fcWT, V_,  512, V_,   0,   512,  316, 5056 };
    combo_trans_k<<<8128, 256, 0, stream>>>(J);
    mean_cvt_k<<<65, 256, 0, stream>>>(a, a_b, mean_ctx, b_ih, b_hh, bias4h, bars);
    gather_emb<<<ROWS/4, 256, 0, stream>>>(caps, embW, xemb_b);
    gemm64t2<<<dim3(8,2,2), 256, 0, stream>>>(mean_ctx, D_, iWh, iWc, H_, h0f, cbuf, H_, ibh, ibc);
    hw0cvt_k<<<B_, 512, 0, stream>>>(h0f, WhcT, xcat_b, hWp);
    // wa_b = bf16(a @ Wa)    (25088 x 512 x 512)
    gemm_mfma<1,0,0,0><<<dim3(4,196), 256, 0, stream>>>(a_b, D_, WaT, D_, wa_b, A_, A_, D_, nullptr);
    // embWih = xemb @ W_ih[:E] + (b_ih+b_hh)   (2432 x 2048 x 256)
    gemm_mfma<0,1,0,0><<<dim3(16,19), 256, 0, stream>>>(xemb_b, E_, WihT, E_, embWih, G4H, G4H, E_, bias4h);

    // ---- loop: 2 kernels/step ----
    for (int t = 0; t < TM1; ++t){
        mega3_k<<<dim3(B_,4), 256, 0, stream>>>(wa_b, a_b, v, beta_W, beta_b, WhcT,
                                                gp, embWih, cbuf, hWp, xcat_b, Hall,
                                                alphas, ebuf, bars, t);
        gates_k<<<dim3(32,8), 256, 0, stream>>>(xcat_b, WcatT, gp);
    }
    lstmfin_k<<<B_, 512, 0, stream>>>(gp, embWih, cbuf, Hall);

    // logits = Hall @ fc_W + fc_b   (2432 x 10000 x 512), NT stores + XCD swizzle
    gemm_mfma<0,1,1,1><<<dim3(1520), 256, 0, stream>>>(Hall, H_, fcWT, H_, out, V_, V_, H_, fc_b);
}

// Round 10
// 1062.536 us; speedup vs baseline: 2.0720x; 1.3977x over previous
//
#include <hip/hip_runtime.h>
#include <hip/hip_bf16.h>
#include <math.h>

#define B_ 128
#define L_ 196
#define D_ 512
#define T_ 20
#define V_ 10000
#define E_ 256
#define H_ 512
#define A_ 512
#define TM1 19
#define ROWS (TM1*B_)      /* 2432 */
#define G4H 2048
#define KCAT 1024
#define LH 98

typedef unsigned short ushort_t;
typedef __attribute__((ext_vector_type(8))) short bf16x8;
typedef __attribute__((ext_vector_type(4))) float f32x4;

__device__ __forceinline__ float fast_tanh(float x){
    float ax = fabsf(x);
    float e = __expf(-2.f*ax);
    float r = __builtin_amdgcn_rcpf(1.f + e);
    return copysignf((1.f - e)*r, x);
}
__device__ __forceinline__ float sigmoidf_(float x){
    return __builtin_amdgcn_rcpf(1.f + __expf(-x));
}
__device__ __forceinline__ ushort_t f2b(float f){
    union{float f; unsigned u;} x; x.f = f;
    unsigned r = x.u + 0x7fffu + ((x.u>>16)&1u);
    return (ushort_t)(r>>16);
}
__device__ __forceinline__ float b2f(ushort_t h){
    union{unsigned u; float f;} x; x.u = ((unsigned)h)<<16;
    return x.f;
}
__device__ __forceinline__ float b2f_lo(unsigned u){ union{unsigned u; float f;} x; x.u = u<<16; return x.f; }
__device__ __forceinline__ float b2f_hi(unsigned u){ union{unsigned u; float f;} x; x.u = u & 0xffff0000u; return x.f; }

#define GL16(gsrc, ldst) __builtin_amdgcn_global_load_lds( \
    (const __attribute__((address_space(1))) unsigned*)(gsrc), \
    (__attribute__((address_space(3))) unsigned*)(ldst), 16, 0, 0)

// ================= bf16 MFMA GEMM: C = A @ BT^T (+bias) =================
// m97-style: double-buffered global_load_lds(16B) staging, 1 barrier/K-step
template<int OUT_BF16, int HAS_BIAS, int NT, int SWZ>
__global__ __launch_bounds__(256)
void gemm_mfma(const ushort_t* __restrict__ A, int lda,
               const ushort_t* __restrict__ BT, int ldb,
               void* __restrict__ Cout, int ldc,
               int N, int K, const float* __restrict__ bias)
{
    __shared__ ushort_t As[2][4096];
    __shared__ ushort_t Bs[2][4096];
    int bm, bn;
    if (SWZ){
        int bid = blockIdx.x;                 // 0..1519
        int swz = (bid & 7)*190 + (bid >> 3); // XCD-contiguous chunks
        int mt = swz % 19, nt = swz / 19;     // nt 0..79
        if (nt >= 79) return;
        bm = mt*128; bn = nt*128;
    } else {
        bm = blockIdx.y * 128; bn = blockIdx.x * 128;
    }
    const int tid = threadIdx.x;
    const int lane = tid & 63;
    const int wave = tid >> 6;
    const int wm = (wave >> 1) * 64;
    const int wn = (wave & 1) * 64;
    const int lrow = lane & 15;
    const int lk8  = (lane >> 4) * 8;
    const int srow = tid >> 2;            // 0..63
    const int skq0 = (tid & 3) * 8;       // element offset within 32-k row
    const int wbase = wave * 512;         // per-wave 512-element LDS chunk

    f32x4 acc[4][4];
    #pragma unroll
    for (int i=0;i<4;i++)
        #pragma unroll
        for (int j=0;j<4;j++) acc[i][j] = (f32x4){0.f,0.f,0.f,0.f};

    const ushort_t* Ab = A  + (size_t)(bm+srow)*lda + skq0;
    const ushort_t* Bb = BT + (size_t)(bn+srow)*ldb + skq0;

    // prologue: issue k0=0 into buf 0
    GL16(Ab,                    &As[0][wbase]);
    GL16(Ab + (size_t)64*lda,   &As[0][2048 + wbase]);
    GL16(Bb,                    &Bs[0][wbase]);
    GL16(Bb + (size_t)64*ldb,   &Bs[0][2048 + wbase]);

    int buf = 0;
    for (int k0 = 0; k0 < K; k0 += 32) {
        asm volatile("s_waitcnt vmcnt(0)" ::: "memory");
        __syncthreads();
        if (k0 + 32 < K){
            int nb = buf ^ 1;
            GL16(Ab + k0 + 32,                  &As[nb][wbase]);
            GL16(Ab + (size_t)64*lda + k0 + 32, &As[nb][2048 + wbase]);
            GL16(Bb + k0 + 32,                  &Bs[nb][wbase]);
            GL16(Bb + (size_t)64*ldb + k0 + 32, &Bs[nb][2048 + wbase]);
        }
        bf16x8 af[4], bfr[4];
        #pragma unroll
        for (int i=0;i<4;i++) af[i]  = *(bf16x8*)&As[buf][(wm + i*16 + lrow)*32 + lk8];
        #pragma unroll
        for (int j=0;j<4;j++) bfr[j] = *(bf16x8*)&Bs[buf][(wn + j*16 + lrow)*32 + lk8];
        #pragma unroll
        for (int i=0;i<4;i++)
            #pragma unroll
            for (int j=0;j<4;j++)
                acc[i][j] = __builtin_amdgcn_mfma_f32_16x16x32_bf16(af[i], bfr[j], acc[i][j], 0, 0, 0);
        buf ^= 1;
    }

    const int rq = (lane >> 4) * 4;
    #pragma unroll
    for (int j=0;j<4;j++){
        int col = bn + wn + j*16 + lrow;
        if (col >= N) continue;
        float bv = HAS_BIAS ? bias[col] : 0.f;
        #pragma unroll
        for (int i=0;i<4;i++){
            #pragma unroll
            for (int q=0;q<4;q++){
                int row = bm + wm + i*16 + rq + q;
                float v = acc[i][j][q] + bv;
                if (OUT_BF16) ((ushort_t*)Cout)[(size_t)row*ldc + col] = f2b(v);
                else if (NT)  __builtin_nontemporal_store(v, &((float*)Cout)[(size_t)row*ldc + col]);
                else          ((float*)Cout)[(size_t)row*ldc + col] = v;
            }
        }
    }
}

// ============ f32 tile GEMM (init path): C = tanh(A@B + bias), z picks job ============
__global__ __launch_bounds__(256) void gemm64t2(const float* __restrict__ A, int lda,
                       const float* __restrict__ B0, const float* __restrict__ B1, int ldb,
                       float* __restrict__ C0, float* __restrict__ C1, int ldc,
                       const float* __restrict__ bias0, const float* __restrict__ bias1)
{
    const float* Bm  = blockIdx.z ? B1 : B0;
    float* C         = blockIdx.z ? C1 : C0;
    const float* bias= blockIdx.z ? bias1 : bias0;
    __shared__ float As[16][65];
    __shared__ float Bs[16][65];
    int bm = blockIdx.y*64, bn = blockIdx.x*64;
    int tid = threadIdx.x;
    int tx = tid & 15, ty = tid >> 4;
    float acc[4][4] = {};
    for (int k0 = 0; k0 < D_; k0 += 16) {
        {
            int r  = tid >> 2;
            int kq = (tid & 3) * 4;
            float4 va = *(const float4*)(A + (size_t)(bm+r)*lda + k0 + kq);
            As[kq+0][r]=va.x; As[kq+1][r]=va.y; As[kq+2][r]=va.z; As[kq+3][r]=va.w;
        }
        {
            int kk = tid >> 4;
            int nq = (tid & 15) * 4;
            float4 vb = *(const float4*)(Bm + (size_t)(k0+kk)*ldb + bn + nq);
            Bs[kk][nq+0]=vb.x; Bs[kk][nq+1]=vb.y; Bs[kk][nq+2]=vb.z; Bs[kk][nq+3]=vb.w;
        }
        __syncthreads();
        #pragma unroll
        for (int k = 0; k < 16; ++k) {
            float a0[4], b0[4];
            #pragma unroll
            for (int i=0;i<4;i++) a0[i] = As[k][ty*4+i];
            #pragma unroll
            for (int j=0;j<4;j++) b0[j] = Bs[k][tx*4+j];
            #pragma unroll
            for (int i=0;i<4;i++)
                #pragma unroll
                for (int j=0;j<4;j++)
                    acc[i][j] = fmaf(a0[i], b0[j], acc[i][j]);
        }
        __syncthreads();
    }
    #pragma unroll
    for (int i=0;i<4;i++){
        int row = bm + ty*4 + i;
        #pragma unroll
        for (int j=0;j<4;j++){
            int col = bn + tx*4 + j;
            C[(size_t)row*ldc + col] = fast_tanh(acc[i][j] + bias[col]);
        }
    }
}

// ================= combined transpose+cvt (all weights in one launch) =================
struct TJob { const float* src; const float* src2; ushort_t* dst;
              int lds, Ksz, Nsz, koff, ldk, nx, nblk; };
struct TJobs { TJob j[6]; };

__global__ __launch_bounds__(256) void combo_trans_k(TJobs J){
    __shared__ float t[32][33];
    int bid = blockIdx.x;
    int ji = 0;
    while (bid >= J.j[ji].nblk){ bid -= J.j[ji].nblk; ji++; }
    const TJob jb = J.j[ji];
    int n0 = (bid % jb.nx)*32, k0 = (bid / jb.nx)*32;
    int tx = threadIdx.x & 31, ty = threadIdx.x >> 5;
    #pragma unroll
    for (int kk = ty; kk < 32; kk += 8){
        int k = k0 + kk, n = n0 + tx;
        float v = 0.f;
        if (k < jb.Ksz && n < jb.Nsz){
            v = jb.src[(size_t)k*jb.lds + n];
            if (jb.src2) v += jb.src2[(size_t)k*jb.lds + n];
        }
        t[kk][tx] = v;
    }
    __syncthreads();
    #pragma unroll
    for (int nn = ty; nn < 32; nn += 8){
        int n = n0 + nn, k = k0 + tx;
        if (k < jb.Ksz) jb.dst[(size_t)n*jb.ldk + jb.koff + k] = f2b(t[tx][nn]);
    }
}

// vectorized one pass over a (float4/lane): column means + bf16 copy; block 64 does bias4h + ebar
__global__ __launch_bounds__(256) void mean_cvt_k(const float* __restrict__ a, ushort_t* __restrict__ a_b,
                                                  float* __restrict__ mc,
                                                  const float* __restrict__ b_ih, const float* __restrict__ b_hh,
                                                  float* __restrict__ bias4h, unsigned* __restrict__ ebar){
    if (blockIdx.x == 64){
        for (int k = threadIdx.x; k < G4H; k += 256) bias4h[k] = b_ih[k] + b_hh[k];
        if (threadIdx.x < B_) ebar[threadIdx.x] = 0u;
        return;
    }
    int idx = blockIdx.x*256 + threadIdx.x;   // b*128 + dq
    int b = idx >> 7, dq = (idx & 127) * 4;
    const float* p = a + (size_t)b*L_*D_ + dq;
    ushort_t* q = a_b + (size_t)b*L_*D_ + dq;
    float4 s = make_float4(0.f,0.f,0.f,0.f);
    for (int l=0;l<L_;l++){
        float4 v = *(const float4*)(p + (size_t)l*D_);
        s.x += v.x; s.y += v.y; s.z += v.z; s.w += v.w;
        ushort_t r[4] = {f2b(v.x),f2b(v.y),f2b(v.z),f2b(v.w)};
        *(uint2*)(q + (size_t)l*D_) = *(uint2*)r;
    }
    const float inv = 1.f/(float)L_;
    float4 o = make_float4(s.x*inv, s.y*inv, s.z*inv, s.w*inv);
    *(float4*)(mc + (size_t)b*D_ + dq) = o;
}

// 4 rows per block
__global__ __launch_bounds__(256) void gather_emb(const int* __restrict__ captions, const float* __restrict__ embW,
                           ushort_t* __restrict__ xemb){
    int i = blockIdx.x*4 + (threadIdx.x >> 6);    // t*B + b
    int lane = threadIdx.x & 63;
    int t = i / B_, b = i - t*B_;
    int cap = captions[b*T_ + t];
    float4 v = ((const float4*)(embW + (size_t)cap*E_))[lane];
    ushort_t r[4] = {f2b(v.x),f2b(v.y),f2b(v.z),f2b(v.w)};
    *(uint2*)(xemb + (size_t)i*E_ + lane*4) = *(uint2*)r;
}

// h0: cvt to xcat + full hWp0 + zero hWp1;  grid B x 512
__global__ __launch_bounds__(512) void hw0cvt_k(const float* __restrict__ h0f,
                        const ushort_t* __restrict__ WhcT,
                        ushort_t* __restrict__ xcat, float* __restrict__ hWp){
    int b = blockIdx.x, tid = threadIdx.x;
    int lane = tid & 63, wave = tid >> 6;
    __shared__ ushort_t hls[512];
    float hv = h0f[b*H_ + tid];
    ushort_t hb = f2b(hv);
    xcat[(size_t)b*KCAT + D_ + tid] = hb;
    hls[tid] = hb;
    hWp[(size_t)(b*2+1)*512 + tid] = 0.f;
    __syncthreads();
    int wn = wave * 64;
    int col16 = lane & 15;
    int khi = (lane >> 4) * 8;
    bool a_on = (col16 == 0);
    f32x4 acc[4];
    #pragma unroll
    for (int f=0;f<4;f++) acc[f] = (f32x4){0.f,0.f,0.f,0.f};
    for (int kk=0; kk<16; kk++){
        bf16x8 af = (bf16x8){0,0,0,0,0,0,0,0};
        if (a_on) af = *(const bf16x8*)&hls[kk*32 + khi];
        #pragma unroll
        for (int f=0;f<4;f++){
            bf16x8 bf = *(const bf16x8*)(WhcT + (size_t)(wn + f*16 + col16)*512 + kk*32 + khi);
            acc[f] = __builtin_amdgcn_mfma_f32_16x16x32_bf16(af, bf, acc[f], 0, 0, 0);
        }
    }
    if (lane < 16){
        #pragma unroll
        for (int f=0;f<4;f++) hWp[(size_t)(b*2+0)*512 + wn + f*16 + lane] = acc[f][0];
    }
}

// ================= mega: lstm(t-1) + hW-partial + attention(t) =================
// grid (B_, 2) x 512; 2 pair-syncs per step via monotonic ebar[b]
__global__ __launch_bounds__(512) void mega2_k(const ushort_t* __restrict__ wa,
                        const ushort_t* __restrict__ a_b,
                        const float* __restrict__ v,
                        const float* __restrict__ beta_W, const float* __restrict__ beta_b,
                        const ushort_t* __restrict__ WhcT,
                        const float* __restrict__ gp, const float* __restrict__ embWih,
                        float* __restrict__ cbuf, float* __restrict__ hWp,
                        ushort_t* __restrict__ xcat, ushort_t* __restrict__ Hall,
                        float* __restrict__ alphas_out, float* __restrict__ ebuf,
                        unsigned* __restrict__ ebar, int t)
{
    const int b = blockIdx.x, half = blockIdx.y;
    const int tid = threadIdx.x;
    const int lane = tid & 63, wave = tid >> 6;
    __shared__ ushort_t hls[256];
    __shared__ float red[512];
    __shared__ float al_s[224];
    __shared__ float part[2][256];

    // ---- phase L: lstm for own j-half + hW K-partial (skip at t==0) ----
    if (t > 0){
        if (tid < 256){
            const int j = half*256 + tid;
            const float* eb = embWih + ((size_t)((t-1)*B_ + b))*G4H;
            float gi = eb[j], gf = eb[H_+j], gg = eb[2*H_+j], go = eb[3*H_+j];
            #pragma unroll
            for (int ks=0; ks<8; ks++){
                const float* g = gp + ((size_t)(ks*B_ + b))*G4H;
                gi += g[j]; gf += g[H_+j]; gg += g[2*H_+j]; go += g[3*H_+j];
            }
            float ig = sigmoidf_(gi), fg = sigmoidf_(gf);
            float g2 = fast_tanh(gg), og = sigmoidf_(go);
            float c = fg*cbuf[b*H_+j] + ig*g2;
            float h = og*fast_tanh(c);
            cbuf[b*H_+j] = c;
            ushort_t hb = f2b(h);
            xcat[(size_t)b*KCAT + D_ + j] = hb;
            Hall[((size_t)(t-1)*B_ + b)*H_ + j] = hb;
            hls[tid] = hb;
        }
        __syncthreads();
        // hWp[half] = h_half @ Whc[half*256 : half*256+256, :]   (K=256 slice)
        int wn = wave * 64;
        int col16 = lane & 15;
        int khi = (lane >> 4) * 8;
        bool a_on = (col16 == 0);
        f32x4 acc[4];
        #pragma unroll
        for (int f=0;f<4;f++) acc[f] = (f32x4){0.f,0.f,0.f,0.f};
        #pragma unroll
        for (int kk=0; kk<8; kk++){
            bf16x8 af = (bf16x8){0,0,0,0,0,0,0,0};
            if (a_on) af = *(const bf16x8*)&hls[kk*32 + khi];
            #pragma unroll
            for (int f=0;f<4;f++){
                bf16x8 bf = *(const bf16x8*)(WhcT + (size_t)(wn + f*16 + col16)*512 + half*256 + kk*32 + khi);
                acc[f] = __builtin_amdgcn_mfma_f32_16x16x32_bf16(af, bf, acc[f], 0, 0, 0);
            }
        }
        if (lane < 16){
            #pragma unroll
            for (int f=0;f<4;f++) hWp[(size_t)(b*2+half)*512 + wn + f*16 + lane] = acc[f][0];
        }
    }
    // ---- pair sync 1: h + hWp complete for both halves ----
    __syncthreads();
    if (tid == 0){
        __threadfence();
        atomicAdd(&ebar[b], 1u);
        const unsigned tgt = 2u*(unsigned)(2*t+1);
        while (__hip_atomic_load(&ebar[b], __ATOMIC_ACQUIRE, __HIP_MEMORY_SCOPE_AGENT) < tgt)
            __builtin_amdgcn_s_sleep(1);
    }
    __syncthreads();
    // ---- phase E: e over own l-half ----
    {
        const float* hp0 = hWp + (size_t)(b*2+0)*512 + lane*8;
        const float* hp1 = hWp + (size_t)(b*2+1)*512 + lane*8;
        float4 p00 = *(const float4*)hp0, p01 = *(const float4*)(hp0+4);
        float4 p10 = *(const float4*)hp1, p11 = *(const float4*)(hp1+4);
        float4 hw0 = make_float4(p00.x+p10.x, p00.y+p10.y, p00.z+p10.z, p00.w+p10.w);
        float4 hw1 = make_float4(p01.x+p11.x, p01.y+p11.y, p01.z+p11.z, p01.w+p11.w);
        const float* vp = v + lane*8;
        float4 v0 = *(const float4*)vp, v1 = *(const float4*)(vp+4);
        const int l0 = half*LH;
        for (int r = wave; r < LH; r += 8){
            int4 raw = *(const int4*)(wa + (((size_t)(b*L_ + l0 + r))<<9) + lane*8);
            const unsigned* u = (const unsigned*)&raw;
            float s;
            s  = fast_tanh(b2f_lo(u[0]) + hw0.x)*v0.x;
            s += fast_tanh(b2f_hi(u[0]) + hw0.y)*v0.y;
            s += fast_tanh(b2f_lo(u[1]) + hw0.z)*v0.z;
            s += fast_tanh(b2f_hi(u[1]) + hw0.w)*v0.w;
            s += fast_tanh(b2f_lo(u[2]) + hw1.x)*v1.x;
            s += fast_tanh(b2f_hi(u[2]) + hw1.y)*v1.y;
            s += fast_tanh(b2f_lo(u[3]) + hw1.z)*v1.z;
            s += fast_tanh(b2f_hi(u[3]) + hw1.w)*v1.w;
            #pragma unroll
            for (int off=32; off; off>>=1) s += __shfl_down(s, off);
            if (lane==0) ebuf[b*L_ + l0 + r] = s;
        }
    }
    // ---- pair sync 2: e complete ----
    __syncthreads();
    if (tid == 0){
        __threadfence();
        atomicAdd(&ebar[b], 1u);
        const unsigned tgt = 2u*(unsigned)(2*t+2);
        while (__hip_atomic_load(&ebar[b], __ATOMIC_ACQUIRE, __HIP_MEMORY_SCOPE_AGENT) < tgt)
            __builtin_amdgcn_s_sleep(1);
    }
    __syncthreads();
    // ---- softmax over all 196 (redundant in both halves) ----
    float ev = (tid < L_) ? ebuf[b*L_ + tid] : -3.0e38f;
    red[tid] = ev; __syncthreads();
    #pragma unroll
    for (int s=256; s; s>>=1){ if (tid<s) red[tid] = fmaxf(red[tid], red[tid+s]); __syncthreads(); }
    float m = red[0]; __syncthreads();
    float pr = (tid < L_) ? __expf(ev - m) : 0.f;
    red[tid] = pr; __syncthreads();
    #pragma unroll
    for (int s=256; s; s>>=1){ if (tid<s) red[tid] += red[tid+s]; __syncthreads(); }
    float inv = 1.f / red[0];
    __syncthreads();
    if (tid < L_) al_s[tid] = pr*inv;
    const int l0 = half*LH;
    if (tid >= l0 && tid < l0 + LH)
        __builtin_nontemporal_store(pr*inv, alphas_out + (size_t)b*TM1*L_ + (size_t)t*L_ + tid);
    // ---- beta ----
    float dv = b2f(xcat[(size_t)b*KCAT + D_ + tid]) * beta_W[tid];
    red[tid] = dv; __syncthreads();
    #pragma unroll
    for (int s=256; s; s>>=1){ if (tid<s) red[tid] += red[tid+s]; __syncthreads(); }
    float beta = sigmoidf_(red[0] + beta_b[0]);
    __syncthreads();
    // ---- ctx: 256 d's per block, l split in two by tid>>8 ----
    const int d  = half*256 + (tid & 255);
    const int lr = tid >> 8;                       // 0/1
    const ushort_t* pa = a_b + (((size_t)(b*L_ + lr*LH))<<9) + d;
    float s0 = 0.f;
    #pragma unroll 7
    for (int i=0; i<LH; ++i) s0 = fmaf(al_s[lr*LH + i], b2f(pa[(size_t)i*512]), s0);
    part[lr][tid & 255] = s0;
    __syncthreads();
    if (tid < 256)
        xcat[(size_t)b*KCAT + half*256 + tid] = f2b(beta*(part[0][tid] + part[1][tid]));
}

// gates partials: grid (32, 8) x 256; tile M128 x N64, K-chunk 128
__global__ __launch_bounds__(256) void gates_k(const ushort_t* __restrict__ xcat,
                        const ushort_t* __restrict__ WcatT, float* __restrict__ gp){
    __shared__ ushort_t As[128*32];
    __shared__ ushort_t Bs[64*32];
    const int bn = blockIdx.x*64;
    const int ks = blockIdx.y;
    const int tid = threadIdx.x;
    const int lane = tid & 63, wave = tid >> 6;
    const int wm = wave*32;
    const int lrow = lane & 15;
    const int lk8 = (lane >> 4) * 8;
    f32x4 acc[2][4];
    #pragma unroll
    for (int i=0;i<2;i++)
        #pragma unroll
        for (int j=0;j<4;j++) acc[i][j] = (f32x4){0.f,0.f,0.f,0.f};

    for (int kk = 0; kk < 4; ++kk){
        int k0 = ks*128 + kk*32;
        int c0 = 2*tid;
        int r0 = c0 >> 2,  kq0 = (c0 & 3)*8;
        int r1 = (c0+1) >> 2, kq1 = ((c0+1) & 3)*8;
        int4 a0 = *(const int4*)(xcat + (size_t)r0*KCAT + k0 + kq0);
        int4 a1 = *(const int4*)(xcat + (size_t)r1*KCAT + k0 + kq1);
        int rb = tid >> 2, kqb = (tid & 3)*8;
        int4 b0 = *(const int4*)(WcatT + (size_t)(bn+rb)*KCAT + k0 + kqb);
        __syncthreads();
        *(int4*)&As[r0*32 + kq0] = a0;
        *(int4*)&As[r1*32 + kq1] = a1;
        *(int4*)&Bs[rb*32 + kqb] = b0;
        __syncthreads();
        bf16x8 af[2], bfr[4];
        #pragma unroll
        for (int i=0;i<2;i++) af[i] = *(bf16x8*)&As[(wm + i*16 + lrow)*32 + lk8];
        #pragma unroll
        for (int j=0;j<4;j++) bfr[j] = *(bf16x8*)&Bs[(j*16 + lrow)*32 + lk8];
        #pragma unroll
        for (int i=0;i<2;i++)
            #pragma unroll
            for (int j=0;j<4;j++)
                acc[i][j] = __builtin_amdgcn_mfma_f32_16x16x32_bf16(af[i], bfr[j], acc[i][j], 0, 0, 0);
    }
    const int rq = (lane >> 4) * 4;
    #pragma unroll
    for (int i=0;i<2;i++){
        #pragma unroll
        for (int j=0;j<4;j++){
            int gcol = bn + j*16 + lrow;
            #pragma unroll
            for (int q=0;q<4;q++){
                int grow = wm + i*16 + rq + q;
                gp[((size_t)(ks*B_ + grow))*G4H + gcol] = acc[i][j][q];
            }
        }
    }
}

// final lstm (h_19 -> Hall[18]); grid B x 512
__global__ __launch_bounds__(512) void lstmfin_k(const float* __restrict__ gp, const float* __restrict__ embWih,
                       const float* __restrict__ cbuf, ushort_t* __restrict__ Hall){
    int b = blockIdx.x, j = threadIdx.x;
    const float* eb = embWih + ((size_t)(18*B_ + b))*G4H;
    float gi = eb[j], gf = eb[H_+j], gg = eb[2*H_+j], go = eb[3*H_+j];
    #pragma unroll
    for (int ks=0; ks<8; ks++){
        const float* g = gp + ((size_t)(ks*B_ + b))*G4H;
        gi += g[j]; gf += g[H_+j]; gg += g[2*H_+j]; go += g[3*H_+j];
    }
    float ig = sigmoidf_(gi), fg = sigmoidf_(gf);
    float g2 = fast_tanh(gg), og = sigmoidf_(go);
    float c = fg*cbuf[b*H_+j] + ig*g2;
    float h = og*fast_tanh(c);
    Hall[((size_t)18*B_ + b)*H_ + j] = f2b(h);
}

extern "C" void kernel_launch(void* const* d_in, const int* in_sizes, int n_in,
                              void* d_out, int out_size, void* d_ws, size_t ws_size,
                              hipStream_t stream) {
    const float* a      = (const float*)d_in[0];
    const int*   caps   = (const int*)  d_in[1];
    const float* embW   = (const float*)d_in[3];
    const float* Wa     = (const float*)d_in[4];
    const float* Wh     = (const float*)d_in[5];
    const float* Wc     = (const float*)d_in[6];
    const float* v      = (const float*)d_in[7];
    const float* beta_W = (const float*)d_in[8];
    const float* beta_b = (const float*)d_in[9];
    const float* W_ih   = (const float*)d_in[10];
    const float* W_hh   = (const float*)d_in[11];
    const float* b_ih   = (const float*)d_in[12];
    const float* b_hh   = (const float*)d_in[13];
    const float* fc_W   = (const float*)d_in[14];
    const float* fc_b   = (const float*)d_in[15];
    const float* iWh    = (const float*)d_in[16];
    const float* ibh    = (const float*)d_in[17];
    const float* iWc    = (const float*)d_in[18];
    const float* ibc    = (const float*)d_in[19];

    float* out    = (float*)d_out;
    float* alphas = out + (size_t)ROWS*V_;

    // d_out scratch (dead before final logits GEMM overwrites it)
    char* ob = (char*)d_out;
    ushort_t* wa_b   = (ushort_t*)(ob);               // 25,690,112 B
    ushort_t* a_b    = (ushort_t*)(ob + 25690112);    // 25,690,112 B
    float*    embWih = (float*)   (ob + 51380224);    // 19,922,944 B (ends 71.3MB < 97.28MB)

    // d_ws layout (byte offsets)
    char* wb = (char*)d_ws;
    float* mean_ctx = (float*)(wb);              // 262144
    float* cbuf     = (float*)(wb + 262144);     // 262144
    float* h0f      = (float*)(wb + 524288);     // 262144
    float* hWp      = (float*)(wb + 786432);     // 524288 (128*2*512 f32)
    float* ebuf     = (float*)(wb + 1310720);    // 102400
    float* bias4h   = (float*)(wb + 1413120);    // 8192
    unsigned* ebar  = (unsigned*)(wb + 1421312); // 1024
    float* gp       = (float*)(wb + 1422336);    // 8388608 (8 ksplits)
    ushort_t* xcat_b = (ushort_t*)(wb + 9810944);   // 262144
    ushort_t* xemb_b = (ushort_t*)(wb + 10073088);  // 1245184
    ushort_t* Hall   = (ushort_t*)(wb + 11318272);  // 2490368
    ushort_t* WaT    = (ushort_t*)(wb + 13808640);  // 524288
    ushort_t* WhcT   = (ushort_t*)(wb + 14332928);  // 524288
    ushort_t* WihT   = (ushort_t*)(wb + 14857216);  // 1048576
    ushort_t* WcatT  = (ushort_t*)(wb + 15905792);  // 4194304
    ushort_t* fcWT   = (ushort_t*)(wb + 20100096);  // 10354688 -> ends ~29.0MB

    // ---- prep ----
    TJobs J;
    J.j[0] = { Wa,   nullptr, WaT,  512, 512, 512,  0,   512,  16, 256 };
    J.j[1] = { Wh,   Wc,      WhcT, 512, 512, 512,  0,   512,  16, 256 };
    J.j[2] = { W_ih, nullptr, WihT, G4H, 256, G4H,  0,   256,  64, 512 };
    J.j[3] = { W_ih + (size_t)E_*G4H, nullptr, WcatT, G4H, 512, G4H, 0,   KCAT, 64, 1024 };
    J.j[4] = { W_hh, nullptr, WcatT, G4H, 512, G4H,  512, KCAT, 64, 1024 };
    J.j[5] = { fc_W, nullptr, fcWT, V_,  512, V_,   0,   512,  316, 5056 };
    combo_trans_k<<<8128, 256, 0, stream>>>(J);
    mean_cvt_k<<<65, 256, 0, stream>>>(a, a_b, mean_ctx, b_ih, b_hh, bias4h, ebar);
    gather_emb<<<ROWS/4, 256, 0, stream>>>(caps, embW, xemb_b);
    gemm64t2<<<dim3(8,2,2), 256, 0, stream>>>(mean_ctx, D_, iWh, iWc, H_, h0f, cbuf, H_, ibh, ibc);
    hw0cvt_k<<<B_, 512, 0, stream>>>(h0f, WhcT, xcat_b, hWp);
    // wa_b = bf16(a @ Wa)    (25088 x 512 x 512)
    gemm_mfma<1,0,0,0><<<dim3(4,196), 256, 0, stream>>>(a_b, D_, WaT, D_, wa_b, A_, A_, D_, nullptr);
    // embWih = xemb @ W_ih[:E] + (b_ih+b_hh)   (2432 x 2048 x 256)
    gemm_mfma<0,1,0,0><<<dim3(16,19), 256, 0, stream>>>(xemb_b, E_, WihT, E_, embWih, G4H, G4H, E_, bias4h);

    // ---- loop: 2 kernels/step ----
    for (int t = 0; t < TM1; ++t){
        mega2_k<<<dim3(B_,2), 512, 0, stream>>>(wa_b, a_b, v, beta_W, beta_b, WhcT,
                                                gp, embWih, cbuf, hWp, xcat_b, Hall,
                                                alphas, ebuf, ebar, t);
        gates_k<<<dim3(32,8), 256, 0, stream>>>(xcat_b, WcatT, gp);
    }
    lstmfin_k<<<B_, 512, 0, stream>>>(gp, embWih, cbuf, Hall);

    // logits = Hall @ fc_W + fc_b   (2432 x 10000 x 512), NT stores + XCD swizzle
    gemm_mfma<0,1,1,1><<<dim3(1520), 256, 0, stream>>>(Hall, H_, fcWT, H_, out, V_, V_, H_, fc_b);
}